// Round 10
// baseline (2414.603 us; speedup 1.0000x reference)
//
#include <hip/hip_runtime.h>

#define EPSN 1e-6f
#define EPSM 1e-5f

typedef __fp16 h2v __attribute__((ext_vector_type(2)));
typedef __fp16 f16x4 __attribute__((ext_vector_type(4)));
typedef float f32x4 __attribute__((ext_vector_type(4)));

// legacy mai-insts spelling; present on gfx908..gfx950 (aux-target builtin in
// host pass: usable, but __has_builtin reports false there -- no guard).
#define MFMA16(a, b, c) __builtin_amdgcn_mfma_f32_16x16x16f16((a), (b), (c), 0, 0, 0)

__device__ __forceinline__ unsigned pkh2(float a, float b) {
    union { h2v h; unsigned u; } v;
    v.h = __builtin_amdgcn_cvt_pkrtz(a, b);
    return v.u;
}

__device__ __forceinline__ float dot2f(unsigned a, unsigned b, float c) {
    union { unsigned u; h2v h; } ua, ub;
    ua.u = a; ub.u = b;
#if __has_builtin(__builtin_amdgcn_fdot2)
    return __builtin_amdgcn_fdot2(ua.h, ub.h, c, false);
#else
    return fmaf((float)ua.h.x, (float)ub.h.x,
                fmaf((float)ua.h.y, (float)ub.h.y, c));
#endif
}

// ---------------- inv L2-norm over channel dim (c=256) ----------------
__global__ __launch_bounds__(256) void invnorm_k(const float* __restrict__ f,
                                                 float* __restrict__ inv)
{
    int pbase = blockIdx.x * 64;
    int pp = threadIdx.x & 63;
    int cc = threadIdx.x >> 6;
    int pos = pbase + pp;
    int b = pos >> 10, ij = pos & 1023;
    const float* fp = f + (size_t)(b * 256) * 1024 + ij;
    float s = 0.f;
    #pragma unroll 8
    for (int k = 0; k < 64; ++k) {
        float v = fp[(size_t)(cc * 64 + k) * 1024];
        s += v * v;
    }
    __shared__ float red[4][64];
    red[cc][pp] = s;
    __syncthreads();
    if (cc == 0) {
        float t = red[0][pp] + red[1][pp] + red[2][pp] + red[3][pp];
        inv[pos] = rsqrtf(t + EPSN);
    }
}

// ---------------- correlation GEMM + relu + softsign (fp32 - precision critical) ----
__global__ __launch_bounds__(256) void corr_k(const float* __restrict__ fa,
                                              const float* __restrict__ fb,
                                              const float* __restrict__ invA,
                                              const float* __restrict__ invB,
                                              float* __restrict__ corr)
{
    __shared__ float As[16][68];
    __shared__ float Bs[16][68];
    int b = blockIdx.z;
    int i0 = blockIdx.y * 64, j0 = blockIdx.x * 64;
    int tid = threadIdx.x;
    int tx = tid & 15, ty = tid >> 4;
    const float* fab = fa + (size_t)b * 256 * 1024;
    const float* fbb = fb + (size_t)b * 256 * 1024;
    const float* ia = invA + b * 1024 + i0;
    const float* ib = invB + b * 1024 + j0;
    float acc[4][4] = {};
    for (int kc = 0; kc < 256; kc += 16) {
        #pragma unroll
        for (int l = 0; l < 4; ++l) {
            int idx = tid + l * 256;
            int r = idx >> 6, cix = idx & 63;
            As[r][cix] = fab[(size_t)(kc + r) * 1024 + i0 + cix] * ia[cix];
            Bs[r][cix] = fbb[(size_t)(kc + r) * 1024 + j0 + cix] * ib[cix];
        }
        __syncthreads();
        #pragma unroll
        for (int k = 0; k < 16; ++k) {
            float4 av = *(const float4*)&As[k][ty * 4];
            float4 bv = *(const float4*)&Bs[k][tx * 4];
            float a[4] = {av.x, av.y, av.z, av.w};
            float bq[4] = {bv.x, bv.y, bv.z, bv.w};
            #pragma unroll
            for (int ii = 0; ii < 4; ++ii)
                #pragma unroll
                for (int jj = 0; jj < 4; ++jj)
                    acc[ii][jj] += a[ii] * bq[jj];
        }
        __syncthreads();
    }
    float* cb = corr + ((size_t)b << 20);
    #pragma unroll
    for (int ii = 0; ii < 4; ++ii) {
        float4 o; float v;
        v = fmaxf(acc[ii][0], 0.f); o.x = v * rsqrtf(v * v + EPSN);
        v = fmaxf(acc[ii][1], 0.f); o.y = v * rsqrtf(v * v + EPSN);
        v = fmaxf(acc[ii][2], 0.f); o.z = v * rsqrtf(v * v + EPSN);
        v = fmaxf(acc[ii][3], 0.f); o.w = v * rsqrtf(v * v + EPSN);
        *(float4*)&cb[(size_t)(i0 + ty * 4 + ii) * 1024 + j0 + tx * 4] = o;
    }
}

// ---------------- mutual matching ----------------
__global__ __launch_bounds__(256) void rowmax_k(const float* __restrict__ c,
                                                float* __restrict__ maxR)
{
    int b = blockIdx.y, i = blockIdx.x, tid = threadIdx.x;
    const float* row = c + ((size_t)b << 20) + ((size_t)i << 10);
    float m = fmaxf(fmaxf(row[tid], row[tid + 256]), fmaxf(row[tid + 512], row[tid + 768]));
    #pragma unroll
    for (int off = 32; off; off >>= 1) m = fmaxf(m, __shfl_down(m, off, 64));
    __shared__ float sred[4];
    if ((tid & 63) == 0) sred[tid >> 6] = m;
    __syncthreads();
    if (tid == 0)
        maxR[b * 1024 + i] = fmaxf(fmaxf(sred[0], sred[1]), fmaxf(sred[2], sred[3]));
}

__global__ __launch_bounds__(256) void colmax_k(const float* __restrict__ c,
                                                float* __restrict__ maxC)
{
    int j = blockIdx.x * 256 + threadIdx.x;
    int r0 = blockIdx.y * 128;
    int b = blockIdx.z;
    const float* cb = c + ((size_t)b << 20);
    float m = 0.f;
    for (int r = 0; r < 128; ++r) m = fmaxf(m, cb[(size_t)(r0 + r) * 1024 + j]);
    atomicMax((int*)&maxC[b * 1024 + j], __float_as_int(m));
}

__global__ __launch_bounds__(256) void mmapply_k(float* __restrict__ c,
                                                 const float* __restrict__ maxR,
                                                 const float* __restrict__ maxC)
{
    int e4 = blockIdx.x * 256 + threadIdx.x;
    int e = e4 * 4;
    int b = e >> 20, i = (e >> 10) & 1023, j0 = e & 1023;
    float4 v = ((float4*)c)[e4];
    float ra = 1.f / (maxR[b * 1024 + i] + EPSM);
    float4 mb = ((const float4*)maxC)[(b * 1024 + j0) >> 2];
    float4 o;
    o.x = v.x * v.x * v.x * ra / (mb.x + EPSM);
    o.y = v.y * v.y * v.y * ra / (mb.y + EPSM);
    o.z = v.z * v.z * v.z * ra / (mb.z + EPSM);
    o.w = v.w * v.w * v.w * ra / (mb.w + EPSM);
    ((float4*)c)[e4] = o;
}

// ---------------- f32 weight pack (layer 1): [CO][CI][81] -> [CI][27][WS] ------
template <int CI, int CO>
__global__ void packw_k(const float* __restrict__ w, float* __restrict__ dst, int perm)
{
    constexpr int WS = (3 * CO + 3) & ~3;
    int idx = blockIdx.x * 256 + threadIdx.x;
    if (idx >= CI * 27 * WS) return;
    int ci = idx / (27 * WS);
    int rem = idx - ci * 27 * WS;
    int d123 = rem / WS;
    int slot = rem - d123 * WS;
    float v = 0.f;
    if (slot < 3 * CO) {
        int d4 = slot / CO, co = slot - d4 * CO;
        int t = d123 * 3 + d4;
        int d1 = t / 27, r2 = t % 27;
        int d2 = r2 / 9, r3 = r2 % 9;
        int d3 = r3 / 3, dd4 = r3 % 3;
        int st = perm ? (d3 * 27 + dd4 * 9 + d1 * 3 + d2) : t;
        v = w[(co * CI + ci) * 81 + st];
    }
    dst[idx] = v;
}

// ---------------- mfma weight pack (layer 2): [10][10][81] -> [81][co16][k16] f16
__global__ void packwm_k(const float* __restrict__ w, unsigned short* __restrict__ dst,
                         int perm)
{
    int idx = blockIdx.x * 256 + threadIdx.x;   // 81*256 = 20736
    if (idx >= 20736) return;
    int tap = idx >> 8;
    int co  = (idx >> 4) & 15;
    int k   = idx & 15;
    float v = 0.f;
    if (co < 10 && k < 10) {
        int d1 = tap / 27, r2 = tap % 27;
        int d2 = r2 / 9, r3 = r2 % 9;
        int d3 = r3 / 3, d4 = r3 % 3;
        int st = perm ? (d3 * 27 + d4 * 9 + d1 * 3 + d2) : tap;
        v = w[(co * 10 + k) * 81 + st];
    }
    union { __fp16 h; unsigned short u; } cv;
    cv.h = (__fp16)v;
    dst[idx] = cv.u;
}

// ---------------- f16-pair weight pack (layer 3): [CO][2*CIP][81] -> [CIP][27][WS]
template <int CIP, int CO>
__global__ void packw2_k(const float* __restrict__ w, unsigned* __restrict__ dst, int perm)
{
    constexpr int WS = (3 * CO + 3) & ~3;
    int idx = blockIdx.x * 256 + threadIdx.x;
    if (idx >= CIP * 27 * WS) return;
    int pp = idx / (27 * WS);
    int rem = idx - pp * 27 * WS;
    int d123 = rem / WS;
    int slot = rem - d123 * WS;
    unsigned v = 0u;
    if (slot < 3 * CO) {
        int d4 = slot / CO, co = slot - d4 * CO;
        int t = d123 * 3 + d4;
        int d1 = t / 27, r2 = t % 27;
        int d2 = r2 / 9, r3 = r2 % 9;
        int d3 = r3 / 3, dd4 = r3 % 3;
        int st = perm ? (d3 * 27 + dd4 * 9 + d1 * 3 + d2) : t;
        float f0 = w[(co * 2 * CIP + 2 * pp) * 81 + st];
        float f1 = w[(co * 2 * CIP + 2 * pp + 1) * 81 + st];
        v = pkh2(f0, f1);
    }
    dst[idx] = v;
}

// ---------------- f32 4D conv (layer 1, CI=1), packed-f16-pair output ----------
// gridDim.y = 2 branches: weight base += by*864, output base += by*5242880 u32
template <int CI, int CO>
__global__ __launch_bounds__(256, 4) void conv4d_k(const float* __restrict__ x,
                                                   const float* __restrict__ wp,
                                                   const float* __restrict__ bias,
                                                   float* __restrict__ y)
{
    constexpr int WS = (3 * CO + 3) & ~3;
    constexpr int NW4 = WS / 4;
    constexpr int SLAB = 34 * 35;
    __shared__ float tile[3 * SLAB];

    int tid = threadIdx.x;
    int f1 = blockIdx.x >> 5, f2 = blockIdx.x & 31;
    int q = tid & 7, yy = tid >> 3;
    int x0 = q << 2;
    const float* wpb = wp + blockIdx.y * (CI * 27 * WS);
    unsigned* ypu = (unsigned*)y + (size_t)blockIdx.y * 5242880;

    for (int e = tid; e < 3 * SLAB; e += 256) tile[e] = 0.f;

    float acc[CO][4];
    #pragma unroll
    for (int co = 0; co < CO; ++co) {
        float bv = bias[co];
        acc[co][0] = bv; acc[co][1] = bv; acc[co][2] = bv; acc[co][3] = bv;
    }

    float bufA[WS], bufB[WS];

#define TAP(U, WB, WN, PF) do {                                               \
        constexpr int u_ = (U);                                               \
        const float* rowb_ = &tile[(u_/3)*SLAB + (yy + u_%3)*35 + x0];        \
        float xs_[6];                                                         \
        _Pragma("unroll") for (int j = 0; j < 6; ++j) xs_[j] = rowb_[j];      \
        if (PF) {                                                             \
            _Pragma("unroll") for (int k = 0; k < NW4; ++k)                   \
                *(float4*)&WN[k*4] =                                          \
                    ((const float4*)(wphase + (u_+1)*WS))[k];                 \
        }                                                                     \
        _Pragma("unroll") for (int d4 = 0; d4 < 3; ++d4)                      \
        _Pragma("unroll") for (int co = 0; co < CO; ++co) {                   \
            float wf_ = WB[d4*CO + co];                                       \
            _Pragma("unroll") for (int p = 0; p < 4; ++p)                     \
                acc[co][p] = fmaf(xs_[p + d4], wf_, acc[co][p]);              \
        }                                                                     \
    } while (0)

    #pragma unroll 1
    for (int ci = 0; ci < CI; ++ci) {
        const float* wci = wpb + ci * 27 * WS;
        #pragma unroll 1
        for (int d1 = 0; d1 < 3; ++d1) {
            int g1 = f1 + d1 - 1;
            bool g1ok = (unsigned)g1 < 32u;
            const float* wphase = wci + d1 * 9 * WS;
            __syncthreads();
            #pragma unroll
            for (int k = 0; k < NW4; ++k)
                *(float4*)&bufA[k*4] = ((const float4*)wphase)[k];
            #pragma unroll
            for (int it = 0; it < 3; ++it) {
                int e = tid + it * 256;
                int s2 = e >> 8, rr = (e >> 3) & 31, qq = e & 7;
                int g2 = f2 + s2 - 1;
                float4 v = {0.f, 0.f, 0.f, 0.f};
                if (g1ok & ((unsigned)g2 < 32u))
                    v = *(const float4*)&x[((size_t)ci << 20) +
                        ((size_t)((g1 << 5) + g2) << 10) + (rr << 5) + (qq << 2)];
                float* t = &tile[s2 * SLAB + (rr + 1) * 35 + 1 + (qq << 2)];
                t[0] = v.x; t[1] = v.y; t[2] = v.z; t[3] = v.w;
            }
            __syncthreads();

            TAP(0, bufA, bufB, true);
            TAP(1, bufB, bufA, true);
            TAP(2, bufA, bufB, true);
            TAP(3, bufB, bufA, true);
            TAP(4, bufA, bufB, true);
            TAP(5, bufB, bufA, true);
            TAP(6, bufA, bufB, true);
            TAP(7, bufB, bufA, true);
            TAP(8, bufA, bufB, false);
        }
    }
#undef TAP

    size_t obase = ((size_t)(f1 * 32 + f2) << 10) + yy * 32 + x0;
    #pragma unroll
    for (int c = 0; c < CO / 2; ++c) {
        uint4 o;
        o.x = pkh2(fmaxf(acc[2*c][0], 0.f), fmaxf(acc[2*c+1][0], 0.f));
        o.y = pkh2(fmaxf(acc[2*c][1], 0.f), fmaxf(acc[2*c+1][1], 0.f));
        o.z = pkh2(fmaxf(acc[2*c][2], 0.f), fmaxf(acc[2*c+1][2], 0.f));
        o.w = pkh2(fmaxf(acc[2*c][3], 0.f), fmaxf(acc[2*c+1][3], 0.f));
        *(uint4*)&ypu[(size_t)c * 1048576 + obase] = o;
    }
}

// ---------------- MFMA 4D conv (layer 2: CI=10, CO=10) ------------------------
// gridDim.y = 2 branches. Sync staging (round-8 form). Wave tile = 4 rows x
// 16 cols (rt=(wv&1)*4, ch=wv>>1); per (d2,d4) the 6 B-rows rt..rt+5 are
// register-cached and feed 12 MFMAs (3 d3 x 4 row-tiles): LDS reads /phase
// drop 108 -> 54 per wave.
__global__ __launch_bounds__(256, 4) void conv4dm_k(const unsigned* __restrict__ xp,
                                                    const unsigned short* __restrict__ wm,
                                                    const float* __restrict__ bias,
                                                    unsigned* __restrict__ yp)
{
    __shared__ unsigned tile[3 * 10 * 34 * 9];   // 9180 u32 = 36720 B

    int tid = threadIdx.x;
    int bx = blockIdx.x;
    int chunk  = bx & 7;
    int within = bx >> 3;
    int f1 = (chunk << 2) | (within >> 7);
    int f2 = (within >> 2) & 31;
    int q  = within & 3;

    const unsigned* xpb = xp + (size_t)blockIdx.y * 5242880;
    const unsigned short* wmb = wm + blockIdx.y * 20736;
    unsigned* ypb = yp + (size_t)blockIdx.y * 5242880;

    int l  = tid & 63;
    int wv = tid >> 6;
    int sl = l & 15;          // A: co-row; B/D: spatial col
    int g  = l >> 4;          // k-group / D row-group
    int rt = (wv & 1) << 2;   // wave's first output row (0 or 4)
    int ch = wv >> 1;         // wave's col half (0 or 1)

    for (int e = tid; e < 9180; e += 256) tile[e] = 0u;

    f32x4 bv;
    #pragma unroll
    for (int e = 0; e < 4; ++e) {
        int co = 4 * g + e;
        bv[e] = (co < 10) ? bias[co] : 0.f;
    }
    f32x4 accv[4] = {bv, bv, bv, bv};

    int qbase = q * 8;

    #pragma unroll 1
    for (int d1 = 0; d1 < 3; ++d1) {
        int g1 = f1 + d1 - 1;
        bool g1ok = (unsigned)g1 < 32u;

        // this phase's 27 A-fragments
        uint2 aw[27];
        #pragma unroll
        for (int t27 = 0; t27 < 27; ++t27)
            aw[t27] = *(const uint2*)&wmb[((d1 * 27 + t27) << 8) + (sl << 4) + (g << 2)];

        __syncthreads();   // previous-phase tile consumers done

        // stage: 240 threads x (5 uint4 loads, 20 LDS writes)
        if (tid < 240) {
            int sk = tid & 7, srg = tid >> 3;
            int sr = srg % 10, ss2 = srg / 10;
            int sc = 1 + (sk << 2);
            int g2 = f2 + ss2 - 1;
            int g3 = qbase + sr - 1;
            uint4 v0 = {0,0,0,0}, v1 = {0,0,0,0}, v2 = {0,0,0,0},
                  v3 = {0,0,0,0}, v4 = {0,0,0,0};
            if (g1ok & ((unsigned)g2 < 32u) & ((unsigned)g3 < 32u)) {
                size_t off = ((size_t)((g1 << 5) + g2) << 10) + (g3 << 5) + (sc - 1);
                v0 = *(const uint4*)&xpb[off];
                v1 = *(const uint4*)&xpb[off + 1048576];
                v2 = *(const uint4*)&xpb[off + 2097152];
                v3 = *(const uint4*)&xpb[off + 3145728];
                v4 = *(const uint4*)&xpb[off + 4194304];
            }
            unsigned* tb = &tile[((ss2 * 10 + sr) * 34 + sc) * 9];
            tb[0] = v0.x; tb[9]  = v0.y; tb[18] = v0.z; tb[27] = v0.w;
            tb[1] = v1.x; tb[10] = v1.y; tb[19] = v1.z; tb[28] = v1.w;
            tb[2] = v2.x; tb[11] = v2.y; tb[20] = v2.z; tb[29] = v2.w;
            tb[3] = v3.x; tb[12] = v3.y; tb[21] = v3.z; tb[30] = v3.w;
            tb[4] = v4.x; tb[13] = v4.y; tb[22] = v4.z; tb[31] = v4.w;
        }
        __syncthreads();

        __builtin_amdgcn_s_setprio(1);
        #pragma unroll
        for (int d2 = 0; d2 < 3; ++d2)
        #pragma unroll
        for (int d4 = 0; d4 < 3; ++d4) {
            // register-cache 6 B rows (rt..rt+5) at col ch*16+sl+d4
            unsigned b0[6], b1[6];
            #pragma unroll
            for (int j = 0; j < 6; ++j) {
                int idx = ((d2 * 10 + rt + j) * 34 + ch * 16 + sl + d4) * 9 + (g << 1);
                b0[j] = tile[idx];
                b1[j] = tile[idx + 1];
            }
            #pragma unroll
            for (int d3 = 0; d3 < 3; ++d3) {
                union { uint2 u; f16x4 h; } A; A.u = aw[d2 * 9 + d3 * 3 + d4];
                #pragma unroll
                for (int j2 = 0; j2 < 4; ++j2) {
                    union { uint2 u; f16x4 h; } B;
                    B.u.x = b0[j2 + d3]; B.u.y = b1[j2 + d3];
                    accv[j2] = MFMA16(A.h, B.h, accv[j2]);
                }
            }
        }
        __builtin_amdgcn_s_setprio(0);
    }

    // epilogue: relu + pack co-pairs into padded LDS, then dense uint4 stores.
    __syncthreads();
#define EPST(ACC, RT, CH) do {                                                \
        int row_ = (RT);                                                      \
        int col_ = (CH) * 16 + sl;                                            \
        float r0 = fmaxf((ACC)[0], 0.f), r1 = fmaxf((ACC)[1], 0.f);           \
        float r2 = fmaxf((ACC)[2], 0.f), r3 = fmaxf((ACC)[3], 0.f);           \
        if (g < 2) {                                                          \
            tile[((2*g)     * 8 + row_) * 33 + col_] = pkh2(r0, r1);          \
            tile[((2*g + 1) * 8 + row_) * 33 + col_] = pkh2(r2, r3);          \
        } else if (g == 2) {                                                  \
            tile[(4 * 8 + row_) * 33 + col_] = pkh2(r0, r1);                  \
        }                                                                     \
    } while (0)
    EPST(accv[0], rt + 0, ch);
    EPST(accv[1], rt + 1, ch);
    EPST(accv[2], rt + 2, ch);
    EPST(accv[3], rt + 3, ch);
#undef EPST
    __syncthreads();

    size_t pbase = ((size_t)((f1 << 5) + f2) << 10);
    #pragma unroll
    for (int u = tid; u < 320; u += 256) {
        int p   = u >> 6;
        int rem = u & 63;
        int row = rem >> 3;
        int cg  = rem & 7;
        const unsigned* src = &tile[(p * 8 + row) * 33 + (cg << 2)];
        uint4 v;
        v.x = src[0]; v.y = src[1]; v.z = src[2]; v.w = src[3];
        *(uint4*)&ypb[(size_t)p * 1048576 + pbase +
                      ((size_t)(qbase + row) << 5) + (cg << 2)] = v;
    }
}

// ---------------- fused layer 3: out = relu(convA) + relu(convB) ---------------
// xp = [2 branches][5 pairs][1M] u32; wp = [2 branches][5][27][4] u32; CO=1.
__global__ __launch_bounds__(256, 4) void conv4dpf_k(const unsigned* __restrict__ xp,
                                                     const unsigned* __restrict__ wp,
                                                     const float* __restrict__ bias,
                                                     float* __restrict__ y)
{
    constexpr int SLAB = 34 * 35;
    __shared__ unsigned tile[3 * SLAB];

    int tid = threadIdx.x;
    int f1 = blockIdx.x >> 5, f2 = blockIdx.x & 31;
    int q = tid & 7, yy = tid >> 3;
    int x0 = q << 2;

    for (int e = tid; e < 3 * SLAB; e += 256) tile[e] = 0u;

    float bv = bias[0];
    float res0 = 0.f, res1 = 0.f, res2 = 0.f, res3 = 0.f;

    #pragma unroll 1
    for (int half = 0; half < 2; ++half) {
        const unsigned* xph = xp + ((size_t)half * 5242880);
        const unsigned* wph = wp + half * 540;
        float a0 = bv, a1 = bv, a2 = bv, a3 = bv;
        #pragma unroll 1
        for (int pp = 0; pp < 5; ++pp) {
            const unsigned* wci = wph + pp * 108;
            #pragma unroll 1
            for (int d1 = 0; d1 < 3; ++d1) {
                int g1 = f1 + d1 - 1;
                bool g1ok = (unsigned)g1 < 32u;
                const unsigned* wphase = wci + d1 * 36;
                __syncthreads();
                #pragma unroll
                for (int it = 0; it < 3; ++it) {
                    int e = tid + it * 256;
                    int s2 = e >> 8, rr = (e >> 3) & 31, qq = e & 7;
                    int g2 = f2 + s2 - 1;
                    uint4 v = {0u, 0u, 0u, 0u};
                    if (g1ok & ((unsigned)g2 < 32u))
                        v = *(const uint4*)&xph[((size_t)pp << 20) +
                            ((size_t)((g1 << 5) + g2) << 10) + (rr << 5) + (qq << 2)];
                    unsigned* t = &tile[s2 * SLAB + (rr + 1) * 35 + 1 + (qq << 2)];
                    t[0] = v.x; t[1] = v.y; t[2] = v.z; t[3] = v.w;
                }
                __syncthreads();

                #pragma unroll
                for (int u = 0; u < 9; ++u) {
                    const unsigned* rowb = &tile[(u / 3) * SLAB + (yy + u % 3) * 35 + x0];
                    unsigned xs0 = rowb[0], xs1 = rowb[1], xs2 = rowb[2];
                    unsigned xs3 = rowb[3], xs4 = rowb[4], xs5 = rowb[5];
                    uint4 wt = *(const uint4*)&wphase[u * 4];   // uniform -> s_load
                    a0 = dot2f(xs0, wt.x, a0); a1 = dot2f(xs1, wt.x, a1);
                    a2 = dot2f(xs2, wt.x, a2); a3 = dot2f(xs3, wt.x, a3);
                    a0 = dot2f(xs1, wt.y, a0); a1 = dot2f(xs2, wt.y, a1);
                    a2 = dot2f(xs3, wt.y, a2); a3 = dot2f(xs4, wt.y, a3);
                    a0 = dot2f(xs2, wt.z, a0); a1 = dot2f(xs3, wt.z, a1);
                    a2 = dot2f(xs4, wt.z, a2); a3 = dot2f(xs5, wt.z, a3);
                }
            }
        }
        res0 += fmaxf(a0, 0.f); res1 += fmaxf(a1, 0.f);
        res2 += fmaxf(a2, 0.f); res3 += fmaxf(a3, 0.f);
    }

    size_t obase = ((size_t)(f1 * 32 + f2) << 10) + yy * 32 + x0;
    float4 o = {res0, res1, res2, res3};
    *(float4*)&y[obase] = o;
}

extern "C" void kernel_launch(void* const* d_in, const int* in_sizes, int n_in,
                              void* d_out, int out_size, void* d_ws, size_t ws_size,
                              hipStream_t stream)
{
    (void)in_sizes; (void)n_in; (void)out_size; (void)ws_size;
    const float* fA = (const float*)d_in[0];
    const float* fB = (const float*)d_in[1];
    const float* w1 = (const float*)d_in[2];
    const float* b1 = (const float*)d_in[3];
    const float* w2 = (const float*)d_in[4];
    const float* b2 = (const float*)d_in[5];
    const float* w3 = (const float*)d_in[6];
    const float* b3 = (const float*)d_in[7];
    float* out = (float*)d_out;
    float* ws = (float*)d_ws;

    size_t o = 0;
    float* invA = ws + o; o += 4096;
    float* invB = ws + o; o += 4096;
    float* maxR = ws + o; o += 4096;
    float* maxC = ws + o; o += 4096;
    float* pw1  = ws + o; o += 2048;                       // 2 x [1][27][32] f32
    unsigned short* wm2 = (unsigned short*)(ws + o); o += 20736;  // 2 x 20736 ushort
    unsigned* pw3 = (unsigned*)(ws + o); o += 1080;        // 2 x [5][27][4] u32
    float* corr = ws + o; o += 4194304;                    // [4][1024][1024]
    unsigned* t1p = (unsigned*)(ws + o); o += 10485760;    // [2 br][5][1M] u32
    unsigned* t2p = (unsigned*)(ws + o); o += 10485760;    // [2 br][5][1M] u32

    invnorm_k<<<64, 256, 0, stream>>>(fA, invA);
    invnorm_k<<<64, 256, 0, stream>>>(fB, invB);
    corr_k<<<dim3(16, 16, 4), 256, 0, stream>>>(fA, fB, invA, invB, corr);

    // mutual matching #1 (in place on corr)
    rowmax_k<<<dim3(1024, 4), 256, 0, stream>>>(corr, maxR);
    (void)hipMemsetAsync(maxC, 0, 4096 * sizeof(float), stream);
    colmax_k<<<dim3(4, 8, 4), 256, 0, stream>>>(corr, maxC);
    mmapply_k<<<4096, 256, 0, stream>>>(corr, maxR, maxC);

    // packed weights (A = normal, B = kernel-axis-permuted symmetric branch)
    packw_k<1, 10><<<4, 256, 0, stream>>>(w1, pw1, 0);
    packw_k<1, 10><<<4, 256, 0, stream>>>(w1, pw1 + 864, 1);
    packwm_k<<<81, 256, 0, stream>>>(w2, wm2, 0);
    packwm_k<<<81, 256, 0, stream>>>(w2, wm2 + 20736, 1);
    packw2_k<5, 1><<<3, 256, 0, stream>>>(w3, pw3, 0);
    packw2_k<5, 1><<<3, 256, 0, stream>>>(w3, pw3 + 540, 1);

    for (int b = 0; b < 4; ++b) {
        const float* xb = corr + (size_t)b * 1048576;
        float* ob = out + (size_t)b * 1048576;
        conv4d_k<1, 10><<<dim3(1024, 2), 256, 0, stream>>>(xb, pw1, b1, (float*)t1p);
        conv4dm_k<<<dim3(4096, 2), 256, 0, stream>>>(t1p, wm2, b2, t2p);
        conv4dpf_k<<<1024, 256, 0, stream>>>(t2p, pw3, b3, ob);
    }

    // mutual matching #2 (in place on out)
    rowmax_k<<<dim3(1024, 4), 256, 0, stream>>>(out, maxR);
    (void)hipMemsetAsync(maxC, 0, 4096 * sizeof(float), stream);
    colmax_k<<<dim3(4, 8, 4), 256, 0, stream>>>(out, maxC);
    mmapply_k<<<4096, 256, 0, stream>>>(out, maxR, maxC);
}